// Round 1
// baseline (381.261 us; speedup 1.0000x reference)
//
#include <hip/hip_runtime.h>
#include <stdint.h>

// Problem constants (B=8, M=4096, N=K=1024, D=1024)
#define RROWS 32768   // B*M
#define KDIM  1024    // N
#define DDIM  1024

typedef __bf16 bf16;
typedef __bf16 bf16x4 __attribute__((ext_vector_type(4)));
typedef __bf16 bf16x8 __attribute__((ext_vector_type(8)));
typedef float  f32x4  __attribute__((ext_vector_type(4)));

typedef __attribute__((address_space(1))) const unsigned int* gas_ptr;
typedef __attribute__((address_space(3))) unsigned int* las_ptr;

// ---------------------------------------------------------------------------
// Prep 1: Gt[d][k] = gamma[k] * w[k][d]  (bf16, transposed so GEMM B-staging
// is a direct global_load_lds copy). 64x64 tiles, LDS transpose.
// ---------------------------------------------------------------------------
__global__ __launch_bounds__(256) void prep_gt(const float* __restrict__ w,
                                               const float* __restrict__ gamma,
                                               bf16* __restrict__ Gt) {
    __shared__ float tile[64][65];
    const int k0 = blockIdx.x * 64;
    const int d0 = blockIdx.y * 64;
    const int t  = threadIdx.x;
    const int col4 = (t & 15) * 4;
    const int rowb = t >> 4;           // 16 rows per round, 4 rounds
#pragma unroll
    for (int r = 0; r < 4; ++r) {
        const int k = rowb + r * 16;
        const float4 v = *(const float4*)&w[(size_t)(k0 + k) * DDIM + d0 + col4];
        const float g = gamma[k0 + k];
        tile[k][col4 + 0] = v.x * g;
        tile[k][col4 + 1] = v.y * g;
        tile[k][col4 + 2] = v.z * g;
        tile[k][col4 + 3] = v.w * g;
    }
    __syncthreads();
    // write Gt rows (d-major, k contiguous): 64 d-rows x 128B
#pragma unroll
    for (int r = 0; r < 2; ++r) {
        const int d  = (t >> 3) + r * 32;
        const int ks = (t & 7) * 8;
        bf16x8 o;
#pragma unroll
        for (int j = 0; j < 8; ++j) o[j] = (bf16)tile[ks + j][d];
        *(bf16x8*)&Gt[(size_t)(d0 + d) * KDIM + k0 + ks] = o;
    }
}

// ---------------------------------------------------------------------------
// Prep 2a: partial sums over k-chunks for gw[d]=sum_k gamma*w and bw[d]=sum_k beta*w
// grid (4 d-chunks of 256, 16 k-chunks of 64)
// ---------------------------------------------------------------------------
__global__ __launch_bounds__(256) void prep_part(const float* __restrict__ w,
                                                 const float* __restrict__ gamma,
                                                 const float* __restrict__ beta,
                                                 float* __restrict__ partG,
                                                 float* __restrict__ partB) {
    const int d  = blockIdx.x * 256 + threadIdx.x;
    const int kc = blockIdx.y;
    float ag = 0.f, ab = 0.f;
    for (int k = kc * 64; k < kc * 64 + 64; ++k) {
        const float wv = w[(size_t)k * DDIM + d];
        ag += gamma[k] * wv;
        ab += beta[k] * wv;
    }
    partG[(size_t)kc * DDIM + d] = ag;
    partB[(size_t)kc * DDIM + d] = ab;
}

// Prep 2b: reduce partials; cvec[d] = sum beta*w + b[d]
__global__ __launch_bounds__(256) void prep_reduce(const float* __restrict__ partG,
                                                   const float* __restrict__ partB,
                                                   const float* __restrict__ b,
                                                   float* __restrict__ gw,
                                                   float* __restrict__ cvec) {
    const int d = blockIdx.x * 256 + threadIdx.x;
    float g = 0.f, a = 0.f;
#pragma unroll
    for (int j = 0; j < 16; ++j) {
        g += partG[(size_t)j * DDIM + d];
        a += partB[(size_t)j * DDIM + d];
    }
    gw[d]   = g;
    cvec[d] = a + b[d];
}

// ---------------------------------------------------------------------------
// Fused GEMM: out[r][d] = rstd_r * (sum_k x[r][k]*Gt[d][k] - mean_r*gw[d]) + cvec[d]
// 128x128 tile, BK=32, 4 waves, 4x4 grid of 16x16x32 bf16 MFMA per wave.
// A (x fp32) staged via VGPR (convert to bf16 + accumulate LN stats).
// B (Gt bf16) staged via global_load_lds width-16.
// ---------------------------------------------------------------------------
#define BM 128
#define BN 128
#define BK 32
#define APAD 40   // As row stride in bf16 elements (80B -> 2-way banks, free)

__global__ __launch_bounds__(256) void fused_gemm(const float* __restrict__ x,
                                                  const bf16* __restrict__ Gt,
                                                  const float* __restrict__ gw,
                                                  const float* __restrict__ cvec,
                                                  float* __restrict__ out) {
    __shared__ __align__(16) bf16 As[BM * APAD];   // 10240 B
    __shared__ __align__(16) bf16 Bs[BM * BK];     // 8192 B
    __shared__ float meanS[BM];
    __shared__ float rstdS[BM];

    const int t     = threadIdx.x;
    const int mTile = blockIdx.x;     // 0..255  (fast dim -> same-Mtile blocks share XCD)
    const int dTile = blockIdx.y;     // 0..7
    const int row0  = mTile * BM;
    const int col0  = dTile * BN;

    const int wave = t >> 6;
    const int lane = t & 63;
    const int wr   = wave >> 1;       // wave row (0/1) -> 64 rows
    const int wc   = wave & 1;        // wave col (0/1) -> 64 cols

    // A staging map: thread covers 4 floats (16B) of one row, 4 rounds of 32 rows
    const int a_row = t >> 3;         // 0..31
    const int a_seg = t & 7;          // *4 floats within BK=32

    float s1[4] = {0.f, 0.f, 0.f, 0.f};
    float s2[4] = {0.f, 0.f, 0.f, 0.f};

    f32x4 acc[4][4];
#pragma unroll
    for (int i = 0; i < 4; ++i)
#pragma unroll
        for (int j = 0; j < 4; ++j) acc[i][j] = (f32x4)0.0f;

    for (int k0 = 0; k0 < KDIM; k0 += BK) {
        __syncthreads();   // previous iter's frag reads done before LDS overwrite

        // ---- B tile: 128 rows(d) x 32 k bf16 = 8KB, 2 x 16B per thread, DMA
#pragma unroll
        for (int j = 0; j < 2; ++j) {
            const int off  = j * 4096 + t * 16;       // byte offset in Bs
            const int brow = off >> 6;                // /64B per row
            const int kseg = (off & 63) >> 1;         // bf16 elem offset: 0,8,16,24
            const bf16* gp = Gt + (size_t)(col0 + brow) * KDIM + k0 + kseg;
            char* lp = (char*)Bs + off;
            __builtin_amdgcn_global_load_lds((gas_ptr)(const void*)gp,
                                             (las_ptr)(void*)lp, 16, 0, 0);
        }

        // ---- A tile: 128 rows x 32 k fp32 -> bf16, accumulate LN stats
#pragma unroll
        for (int r = 0; r < 4; ++r) {
            const int row = r * 32 + a_row;
            const float4 v = *(const float4*)&x[(size_t)(row0 + row) * KDIM + k0 + a_seg * 4];
            s1[r] += v.x + v.y + v.z + v.w;
            s2[r] += v.x * v.x + v.y * v.y + v.z * v.z + v.w * v.w;
            bf16x4 pk;
            pk[0] = (bf16)v.x; pk[1] = (bf16)v.y; pk[2] = (bf16)v.z; pk[3] = (bf16)v.w;
            *(bf16x4*)&As[row * APAD + a_seg * 4] = pk;   // 8B ds_write
        }

        __syncthreads();

        // ---- compute: 4 A-frags + 4 B-frags (ds_read_b128 each), 16 MFMA
        bf16x8 af[4], bfr[4];
        const int arow = wr * 64 + (lane & 15);
        const int brow = wc * 64 + (lane & 15);
        const int koff = (lane >> 4) * 8;
#pragma unroll
        for (int i = 0; i < 4; ++i)
            af[i] = *(const bf16x8*)&As[(arow + i * 16) * APAD + koff];
#pragma unroll
        for (int j = 0; j < 4; ++j)
            bfr[j] = *(const bf16x8*)&Bs[(brow + j * 16) * BK + koff];
#pragma unroll
        for (int i = 0; i < 4; ++i)
#pragma unroll
            for (int j = 0; j < 4; ++j)
                acc[i][j] = __builtin_amdgcn_mfma_f32_16x16x32_bf16(af[i], bfr[j], acc[i][j], 0, 0, 0);
    }

    // ---- LN stats finalize: reduce over the 8 threads (a_seg) sharing each row
#pragma unroll
    for (int r = 0; r < 4; ++r) {
        float a = s1[r], b = s2[r];
#pragma unroll
        for (int ofs = 1; ofs < 8; ofs <<= 1) {
            a += __shfl_xor(a, ofs, 64);
            b += __shfl_xor(b, ofs, 64);
        }
        if (a_seg == 0) {
            const int row = r * 32 + a_row;
            const float mean = a * (1.0f / KDIM);
            const float var  = b * (1.0f / KDIM) - mean * mean;
            meanS[row] = mean;
            rstdS[row] = rsqrtf(var + 1e-5f);
        }
    }
    __syncthreads();

    // ---- epilogue: out = rstd*(acc - mean*gw[d]) + cvec[d]
    const int lr = (lane >> 4) * 4;   // C/D layout: row=(lane>>4)*4+reg, col=lane&15
    const int lc = lane & 15;
#pragma unroll
    for (int j = 0; j < 4; ++j) {
        const int colL = wc * 64 + j * 16 + lc;
        const int col  = col0 + colL;
        const float gwv = gw[col];
        const float cv  = cvec[col];
#pragma unroll
        for (int i = 0; i < 4; ++i) {
#pragma unroll
            for (int rg = 0; rg < 4; ++rg) {
                const int rowL = wr * 64 + i * 16 + lr + rg;
                const float v = rstdS[rowL] * (acc[i][j][rg] - meanS[rowL] * gwv) + cv;
                out[(size_t)(row0 + rowL) * DDIM + col] = v;
            }
        }
    }
}

// ---------------------------------------------------------------------------
extern "C" void kernel_launch(void* const* d_in, const int* in_sizes, int n_in,
                              void* d_out, int out_size, void* d_ws, size_t ws_size,
                              hipStream_t stream) {
    const float* x     = (const float*)d_in[0];   // [8,4096,1024]
    const float* w     = (const float*)d_in[1];   // [1024,1024]
    const float* b     = (const float*)d_in[2];   // [1024]
    const float* gamma = (const float*)d_in[3];   // [1024]
    const float* beta  = (const float*)d_in[4];   // [1024]
    float* out = (float*)d_out;                   // [8,4096,1024]

    char* ws = (char*)d_ws;
    bf16*  Gt    = (bf16*)ws;                               // 2 MB
    float* partG = (float*)(ws + (2u << 20));               // 64 KB
    float* partB = (float*)(ws + (2u << 20) + (64u << 10)); // 64 KB
    float* gw    = (float*)(ws + (2u << 20) + (128u << 10));// 4 KB
    float* cvec  = (float*)(ws + (2u << 20) + (132u << 10));// 4 KB

    prep_gt<<<dim3(16, 16), 256, 0, stream>>>(w, gamma, Gt);
    prep_part<<<dim3(4, 16), 256, 0, stream>>>(w, gamma, beta, partG, partB);
    prep_reduce<<<4, 256, 0, stream>>>(partG, partB, b, gw, cvec);
    fused_gemm<<<dim3(256, 8), 256, 0, stream>>>(x, Gt, gw, cvec, out);
}

// Round 2
// 339.092 us; speedup vs baseline: 1.1244x; 1.1244x over previous
//
#include <hip/hip_runtime.h>
#include <stdint.h>

// Problem constants (B=8, M=4096, N=K=1024, D=1024)
#define RROWS 32768   // B*M
#define KDIM  1024    // N
#define DDIM  1024

typedef __bf16 bf16;
typedef __bf16 bf16x4 __attribute__((ext_vector_type(4)));
typedef __bf16 bf16x8 __attribute__((ext_vector_type(8)));
typedef float  f32x4  __attribute__((ext_vector_type(4)));

typedef __attribute__((address_space(1))) const unsigned int* gas_ptr;
typedef __attribute__((address_space(3))) unsigned int* las_ptr;

// ---------------------------------------------------------------------------
// Prep 1: Gt[d][k] = gamma[k] * w[k][d]  (bf16, transposed). 64x64 LDS tiles.
// ---------------------------------------------------------------------------
__global__ __launch_bounds__(256) void prep_gt(const float* __restrict__ w,
                                               const float* __restrict__ gamma,
                                               bf16* __restrict__ Gt) {
    __shared__ float tile[64][65];
    const int k0 = blockIdx.x * 64;
    const int d0 = blockIdx.y * 64;
    const int t  = threadIdx.x;
    const int col4 = (t & 15) * 4;
    const int rowb = t >> 4;
#pragma unroll
    for (int r = 0; r < 4; ++r) {
        const int k = rowb + r * 16;
        const float4 v = *(const float4*)&w[(size_t)(k0 + k) * DDIM + d0 + col4];
        const float g = gamma[k0 + k];
        tile[k][col4 + 0] = v.x * g;
        tile[k][col4 + 1] = v.y * g;
        tile[k][col4 + 2] = v.z * g;
        tile[k][col4 + 3] = v.w * g;
    }
    __syncthreads();
#pragma unroll
    for (int r = 0; r < 2; ++r) {
        const int d  = (t >> 3) + r * 32;
        const int ks = (t & 7) * 8;
        bf16x8 o;
#pragma unroll
        for (int j = 0; j < 8; ++j) o[j] = (bf16)tile[ks + j][d];
        *(bf16x8*)&Gt[(size_t)(d0 + d) * KDIM + k0 + ks] = o;
    }
}

// ---------------------------------------------------------------------------
// Prep 2a/2b: gw[d] = sum_k gamma*w (fallback path only), cvec[d] = sum_k beta*w + b
// ---------------------------------------------------------------------------
__global__ __launch_bounds__(256) void prep_part(const float* __restrict__ w,
                                                 const float* __restrict__ gamma,
                                                 const float* __restrict__ beta,
                                                 float* __restrict__ partG,
                                                 float* __restrict__ partB) {
    const int d  = blockIdx.x * 256 + threadIdx.x;
    const int kc = blockIdx.y;
    float ag = 0.f, ab = 0.f;
    for (int k = kc * 64; k < kc * 64 + 64; ++k) {
        const float wv = w[(size_t)k * DDIM + d];
        ag += gamma[k] * wv;
        ab += beta[k] * wv;
    }
    partG[(size_t)kc * DDIM + d] = ag;
    partB[(size_t)kc * DDIM + d] = ab;
}

__global__ __launch_bounds__(256) void prep_reduce(const float* __restrict__ partG,
                                                   const float* __restrict__ partB,
                                                   const float* __restrict__ b,
                                                   float* __restrict__ gw,
                                                   float* __restrict__ cvec) {
    const int d = blockIdx.x * 256 + threadIdx.x;
    float g = 0.f, a = 0.f;
#pragma unroll
    for (int j = 0; j < 16; ++j) {
        g += partG[(size_t)j * DDIM + d];
        a += partB[(size_t)j * DDIM + d];
    }
    gw[d]   = g;
    cvec[d] = a + b[d];
}

// ---------------------------------------------------------------------------
// Pass 1: per-row LN stats + normalize + convert to bf16.
// One wave per row; 4 rows per 256-thread block. xb[r][k] = (x-mean)*rstd.
// ---------------------------------------------------------------------------
__global__ __launch_bounds__(256) void ln_convert(const float* __restrict__ x,
                                                  bf16* __restrict__ xb) {
    const int wave = threadIdx.x >> 6;
    const int lane = threadIdx.x & 63;
    const int row  = blockIdx.x * 4 + wave;
    const float4* xr = (const float4*)(x + (size_t)row * KDIM);

    float4 v[4];
    float s1 = 0.f, s2 = 0.f;
#pragma unroll
    for (int j = 0; j < 4; ++j) {
        v[j] = xr[lane + j * 64];
        s1 += v[j].x + v[j].y + v[j].z + v[j].w;
        s2 += v[j].x * v[j].x + v[j].y * v[j].y + v[j].z * v[j].z + v[j].w * v[j].w;
    }
#pragma unroll
    for (int ofs = 1; ofs < 64; ofs <<= 1) {
        s1 += __shfl_xor(s1, ofs, 64);
        s2 += __shfl_xor(s2, ofs, 64);
    }
    const float mean = s1 * (1.0f / KDIM);
    const float var  = s2 * (1.0f / KDIM) - mean * mean;
    const float rstd = rsqrtf(var + 1e-5f);

    bf16x4* xo = (bf16x4*)(xb + (size_t)row * KDIM);
#pragma unroll
    for (int j = 0; j < 4; ++j) {
        bf16x4 o;
        o[0] = (bf16)((v[j].x - mean) * rstd);
        o[1] = (bf16)((v[j].y - mean) * rstd);
        o[2] = (bf16)((v[j].z - mean) * rstd);
        o[3] = (bf16)((v[j].w - mean) * rstd);
        xo[lane + j * 64] = o;
    }
}

// ---------------------------------------------------------------------------
// Pass 2: pure bf16 GEMM, out[r][d] = sum_k xb[r][k]*Gt[d][k] + cvec[d].
// 128x128 tile, BK=64, both tiles DMA-staged (global_load_lds width 16) with
// XOR chunk swizzle: 16B chunk (row,q) stored at slot q^(row&7). Frag reads
// are then conflict-free (8 slots x 2 rows -> 2-way max = free).
// ---------------------------------------------------------------------------
#define BM 128
#define BN 128
#define BK 64

__global__ __launch_bounds__(256) void gemm_bt(const bf16* __restrict__ xb,
                                               const bf16* __restrict__ Gt,
                                               const float* __restrict__ cvec,
                                               float* __restrict__ out) {
    __shared__ __align__(16) bf16 As[BM * BK];   // 16 KB
    __shared__ __align__(16) bf16 Bs[BN * BK];   // 16 KB

    const int t     = threadIdx.x;
    const int dTile = blockIdx.x;     // 0..7 (fast)
    const int mTile = blockIdx.y;     // 0..255
    const int row0  = mTile * BM;
    const int col0  = dTile * BN;

    const int wave = t >> 6;
    const int lane = t & 63;
    const int wr   = wave >> 1;
    const int wc   = wave & 1;
    const int quad = lane >> 4;
    const int r16  = lane & 15;

    f32x4 acc[4][4];
#pragma unroll
    for (int i = 0; i < 4; ++i)
#pragma unroll
        for (int j = 0; j < 4; ++j) acc[i][j] = (f32x4)0.0f;

    for (int k0 = 0; k0 < KDIM; k0 += BK) {
        __syncthreads();

        // A tile: 128 rows x 64 k bf16 = 16KB = 1024 16B chunks, 4/thread
#pragma unroll
        for (int j = 0; j < 4; ++j) {
            const int ci   = j * 256 + t;
            const int row  = ci >> 3;
            const int slot = ci & 7;
            const int q    = slot ^ (row & 7);
            const bf16* gp = xb + (size_t)(row0 + row) * KDIM + k0 + q * 8;
            char* lp = (char*)As + ci * 16;
            __builtin_amdgcn_global_load_lds((gas_ptr)(const void*)gp,
                                             (las_ptr)(void*)lp, 16, 0, 0);
        }
        // B tile: same shape from Gt
#pragma unroll
        for (int j = 0; j < 4; ++j) {
            const int ci   = j * 256 + t;
            const int row  = ci >> 3;
            const int slot = ci & 7;
            const int q    = slot ^ (row & 7);
            const bf16* gp = Gt + (size_t)(col0 + row) * KDIM + k0 + q * 8;
            char* lp = (char*)Bs + ci * 16;
            __builtin_amdgcn_global_load_lds((gas_ptr)(const void*)gp,
                                             (las_ptr)(void*)lp, 16, 0, 0);
        }

        __syncthreads();

#pragma unroll
        for (int kk = 0; kk < 2; ++kk) {
            bf16x8 af[4], bfr[4];
#pragma unroll
            for (int i = 0; i < 4; ++i) {
                const int row  = wr * 64 + i * 16 + r16;
                const int slot = (kk * 4 + quad) ^ (row & 7);
                af[i] = *(const bf16x8*)&As[row * BK + slot * 8];
            }
#pragma unroll
            for (int j = 0; j < 4; ++j) {
                const int row  = wc * 64 + j * 16 + r16;
                const int slot = (kk * 4 + quad) ^ (row & 7);
                bfr[j] = *(const bf16x8*)&Bs[row * BK + slot * 8];
            }
#pragma unroll
            for (int i = 0; i < 4; ++i)
#pragma unroll
                for (int j = 0; j < 4; ++j)
                    acc[i][j] = __builtin_amdgcn_mfma_f32_16x16x32_bf16(af[i], bfr[j], acc[i][j], 0, 0, 0);
        }
    }

    // epilogue: + cvec[d]
    const int lr = quad * 4;
    const int lc = r16;
#pragma unroll
    for (int j = 0; j < 4; ++j) {
        const int col = col0 + wc * 64 + j * 16 + lc;
        const float cv = cvec[col];
#pragma unroll
        for (int i = 0; i < 4; ++i) {
#pragma unroll
            for (int rg = 0; rg < 4; ++rg) {
                const int row = row0 + wr * 64 + i * 16 + lr + rg;
                out[(size_t)row * DDIM + col] = acc[i][j][rg] + cv;
            }
        }
    }
}

// ---------------------------------------------------------------------------
// Fallback (small ws): round-1 fused kernel — LN stats inline, gw/mean epilogue.
// ---------------------------------------------------------------------------
#define FBK 32
#define APAD 40

__global__ __launch_bounds__(256) void fused_gemm(const float* __restrict__ x,
                                                  const bf16* __restrict__ Gt,
                                                  const float* __restrict__ gw,
                                                  const float* __restrict__ cvec,
                                                  float* __restrict__ out) {
    __shared__ __align__(16) bf16 As2[BM * APAD];
    __shared__ __align__(16) bf16 Bs2[BM * FBK];
    __shared__ float meanS[BM];
    __shared__ float rstdS[BM];

    const int t     = threadIdx.x;
    const int mTile = blockIdx.x;
    const int dTile = blockIdx.y;
    const int row0  = mTile * BM;
    const int col0  = dTile * BN;
    const int wave = t >> 6;
    const int lane = t & 63;
    const int wr   = wave >> 1;
    const int wc   = wave & 1;
    const int a_row = t >> 3;
    const int a_seg = t & 7;

    float s1[4] = {0.f, 0.f, 0.f, 0.f};
    float s2[4] = {0.f, 0.f, 0.f, 0.f};
    f32x4 acc[4][4];
#pragma unroll
    for (int i = 0; i < 4; ++i)
#pragma unroll
        for (int j = 0; j < 4; ++j) acc[i][j] = (f32x4)0.0f;

    for (int k0 = 0; k0 < KDIM; k0 += FBK) {
        __syncthreads();
#pragma unroll
        for (int j = 0; j < 2; ++j) {
            const int off  = j * 4096 + t * 16;
            const int brow = off >> 6;
            const int kseg = (off & 63) >> 1;
            const bf16* gp = Gt + (size_t)(col0 + brow) * KDIM + k0 + kseg;
            char* lp = (char*)Bs2 + off;
            __builtin_amdgcn_global_load_lds((gas_ptr)(const void*)gp,
                                             (las_ptr)(void*)lp, 16, 0, 0);
        }
#pragma unroll
        for (int r = 0; r < 4; ++r) {
            const int row = r * 32 + a_row;
            const float4 v = *(const float4*)&x[(size_t)(row0 + row) * KDIM + k0 + a_seg * 4];
            s1[r] += v.x + v.y + v.z + v.w;
            s2[r] += v.x * v.x + v.y * v.y + v.z * v.z + v.w * v.w;
            bf16x4 pk;
            pk[0] = (bf16)v.x; pk[1] = (bf16)v.y; pk[2] = (bf16)v.z; pk[3] = (bf16)v.w;
            *(bf16x4*)&As2[row * APAD + a_seg * 4] = pk;
        }
        __syncthreads();

        bf16x8 af[4], bfr[4];
        const int arow = wr * 64 + (lane & 15);
        const int brow = wc * 64 + (lane & 15);
        const int koff = (lane >> 4) * 8;
#pragma unroll
        for (int i = 0; i < 4; ++i)
            af[i] = *(const bf16x8*)&As2[(arow + i * 16) * APAD + koff];
#pragma unroll
        for (int j = 0; j < 4; ++j)
            bfr[j] = *(const bf16x8*)&Bs2[(brow + j * 16) * FBK + koff];
#pragma unroll
        for (int i = 0; i < 4; ++i)
#pragma unroll
            for (int j = 0; j < 4; ++j)
                acc[i][j] = __builtin_amdgcn_mfma_f32_16x16x32_bf16(af[i], bfr[j], acc[i][j], 0, 0, 0);
    }

#pragma unroll
    for (int r = 0; r < 4; ++r) {
        float a = s1[r], b = s2[r];
#pragma unroll
        for (int ofs = 1; ofs < 8; ofs <<= 1) {
            a += __shfl_xor(a, ofs, 64);
            b += __shfl_xor(b, ofs, 64);
        }
        if (a_seg == 0) {
            const int row = r * 32 + a_row;
            const float mean = a * (1.0f / KDIM);
            const float var  = b * (1.0f / KDIM) - mean * mean;
            meanS[row] = mean;
            rstdS[row] = rsqrtf(var + 1e-5f);
        }
    }
    __syncthreads();

    const int lr = (lane >> 4) * 4;
    const int lc = lane & 15;
#pragma unroll
    for (int j = 0; j < 4; ++j) {
        const int col = col0 + wc * 64 + j * 16 + lc;
        const float gwv = gw[col];
        const float cv  = cvec[col];
#pragma unroll
        for (int i = 0; i < 4; ++i) {
#pragma unroll
            for (int rg = 0; rg < 4; ++rg) {
                const int rowL = wr * 64 + i * 16 + lr + rg;
                const float vv = rstdS[rowL] * (acc[i][j][rg] - meanS[rowL] * gwv) + cv;
                out[(size_t)(row0 + rowL) * DDIM + col] = vv;
            }
        }
    }
}

// ---------------------------------------------------------------------------
extern "C" void kernel_launch(void* const* d_in, const int* in_sizes, int n_in,
                              void* d_out, int out_size, void* d_ws, size_t ws_size,
                              hipStream_t stream) {
    const float* x     = (const float*)d_in[0];
    const float* w     = (const float*)d_in[1];
    const float* b     = (const float*)d_in[2];
    const float* gamma = (const float*)d_in[3];
    const float* beta  = (const float*)d_in[4];
    float* out = (float*)d_out;

    char* ws = (char*)d_ws;
    // Layout: xb (64MB) | Gt (2MB) | partG (64KB) | partB (64KB) | gw (4KB) | cvec (4KB)
    const size_t XB_B = (size_t)RROWS * KDIM * sizeof(bf16);   // 67,108,864
    bf16*  xb    = (bf16*)ws;
    bf16*  Gt    = (bf16*)(ws + XB_B);
    float* partG = (float*)(ws + XB_B + (2u << 20));
    float* partB = (float*)(ws + XB_B + (2u << 20) + (64u << 10));
    float* gw    = (float*)(ws + XB_B + (2u << 20) + (128u << 10));
    float* cvec  = (float*)(ws + XB_B + (2u << 20) + (132u << 10));

    const bool big_ws = ws_size >= XB_B + (3u << 20);

    if (big_ws) {
        prep_gt<<<dim3(16, 16), 256, 0, stream>>>(w, gamma, Gt);
        prep_part<<<dim3(4, 16), 256, 0, stream>>>(w, gamma, beta, partG, partB);
        prep_reduce<<<4, 256, 0, stream>>>(partG, partB, b, gw, cvec);
        ln_convert<<<RROWS / 4, 256, 0, stream>>>(x, xb);
        gemm_bt<<<dim3(8, 256), 256, 0, stream>>>(xb, Gt, cvec, out);
    } else {
        // small scratch: round-1 fused path (needs ~2.2MB)
        bf16*  Gt2    = (bf16*)ws;
        float* partG2 = (float*)(ws + (2u << 20));
        float* partB2 = (float*)(ws + (2u << 20) + (64u << 10));
        float* gw2    = (float*)(ws + (2u << 20) + (128u << 10));
        float* cvec2  = (float*)(ws + (2u << 20) + (132u << 10));
        prep_gt<<<dim3(16, 16), 256, 0, stream>>>(w, gamma, Gt2);
        prep_part<<<dim3(4, 16), 256, 0, stream>>>(w, gamma, beta, partG2, partB2);
        prep_reduce<<<4, 256, 0, stream>>>(partG2, partB2, b, gw2, cvec2);
        fused_gemm<<<dim3(256, 8), 256, 0, stream>>>(x, Gt2, gw2, cvec2, out);
    }
}